// Round 10
// baseline (458.851 us; speedup 1.0000x reference)
//
#include <hip/hip_runtime.h>
#include <hip/hip_bf16.h>

// LSTM: B=1024, T=512, I=4, H=128, O=4. Gate order i,f,g,o (PyTorch).
// out = h_T @ W_fc^T + b_fc
//
// 64 blocks x 16 batch rows, full T-loop on-chip; per step gates = W@[h|x]^T
// via mfma_f32_16x16x32_bf16 (K-major issue), x-projection as register MFMAs
// folded into next step's acc init. Thread owns 4 consecutive hidden cols of
// one batch row for all gates -> in-register c/h update.
//
// ROUND 10 (bisect): r8/r9's macro/peel/pointer skeleton NaN'd even with the
// corrected Newton seed -> skeleton is a second defect carrier (like r4's
// template skeleton). This kernel is the EXACT r7-passing skeleton (runtime
// cur/nxt loop, Albuf[...] indexing, launch_bounds(512)) with ONE change:
// activations use packed-f32 Newton reciprocal (correct [1,2] seed
// r0 = 0.9571068 - 0.5*s, 2 Newton steps -> rel err 5.5e-5) instead of
// v_rcp trans ops. If this NaNs, the pk-activation code is the carrier.

#define Tlen 512
#define Iin  4
#define Hdim 128
#define Odim 4

typedef __attribute__((ext_vector_type(8))) short bf16x8;
typedef __attribute__((ext_vector_type(4))) float f32x4;
typedef __attribute__((ext_vector_type(2))) float f32x2;
typedef __attribute__((ext_vector_type(2))) unsigned uint2v;
typedef __attribute__((ext_vector_type(4))) unsigned uint4v;

static __device__ __forceinline__ short f2bf(float f) {
  union { float f; unsigned u; } v; v.f = f;
  unsigned u = v.u;
  return (short)((u + 0x7FFFu + ((u >> 16) & 1u)) >> 16);  // RNE
}
static __device__ __forceinline__ unsigned cvt_pk_bf16(float lo, float hi) {
  unsigned r;
  asm("v_cvt_pk_bf16_f32 %0, %1, %2" : "=v"(r) : "v"(lo), "v"(hi));
  return r;
}
static __device__ __forceinline__ float ex2(float x) { return __builtin_amdgcn_exp2f(x); }

static __device__ __forceinline__ f32x2 mk2(float a, float b) { f32x2 r; r.x = a; r.y = b; return r; }
static __device__ __forceinline__ f32x2 sp2(float v) { f32x2 r; r.x = v; r.y = v; return r; }
static __device__ __forceinline__ f32x2 pkfma(f32x2 a, f32x2 b, f32x2 c) {
  return __builtin_elementwise_fma(a, b, c);
}
// r = 1/(1+s), s in [0,1] (d = 1+s in [1,2]): minimax linear seed on [1,2]
// r0 = 1.45711 - 0.5*d = 0.9571068 - 0.5*s (|rel err| <= 8.6%, POSITIVE on
// the whole domain), then 2 Newton steps (packed fma) -> rel err 5.5e-5.
static __device__ __forceinline__ f32x2 rcp1p(f32x2 s) {
  f32x2 nd = pkfma(s, sp2(-1.0f), sp2(-1.0f));          // -(1+s) = -d
  f32x2 r  = pkfma(s, sp2(-0.5f), sp2(0.9571067812f));
  r = r * pkfma(nd, r, sp2(2.0f));
  r = r * pkfma(nd, r, sp2(2.0f));
  return r;
}
static __device__ __forceinline__ f32x2 exp2negabs(f32x2 u) {
  return mk2(ex2(-__builtin_fabsf(u.x)), ex2(-__builtin_fabsf(u.y)));
}
static __device__ __forceinline__ f32x2 sgn2(f32x2 u) {
  return mk2(__builtin_copysignf(1.0f, u.x), __builtin_copysignf(1.0f, u.y));
}
// sigmoid(x), u = log2e*x: r = 1/(1+2^-|u|) in [0.5,1]; sig = 0.5+sgn*(r-0.5)
static __device__ __forceinline__ f32x2 sigm2(f32x2 u) {
  f32x2 r = rcp1p(exp2negabs(u));
  return pkfma(sgn2(u), r + sp2(-0.5f), sp2(0.5f));
}
// tanh(z), u = 2*log2e*z: tanh = sgn*(2r-1)
static __device__ __forceinline__ f32x2 tanh2s(f32x2 u) {
  f32x2 r = rcp1p(exp2negabs(u));
  return sgn2(u) * pkfma(r, sp2(2.0f), sp2(-1.0f));
}

#define MFMA __builtin_amdgcn_mfma_f32_16x16x32_bf16

__global__ __launch_bounds__(512) void lstm_kernel(
    const float* __restrict__ x, const float* __restrict__ W_ih,
    const float* __restrict__ W_hh, const float* __restrict__ b_ih,
    const float* __restrict__ b_hh, const float* __restrict__ W_fc,
    const float* __restrict__ b_fc, float* __restrict__ out) {
  // h double-buffer: [buf][batch row][k]; row stride 168 shorts = 336 B
  // (b128-aligned; measured-benign banking). Cols 0..127 = h, rest unused/0.
  __shared__ alignas(16) short Albuf[2][16][168];
  __shared__ float hfin[16][Hdim];

  const int tid  = threadIdx.x;
  const int wid  = tid >> 6;    // wave 0..7 -> hidden cols wid*16..+15
  const int lane = tid & 63;
  const int m16  = lane & 15;   // batch row / weight row within tile
  const int grp  = lane >> 4;   // k-group 0..3
  const int bbase = blockIdx.x * 16;
  const float L2E = 1.4426950408889634f;

  // ---- weight fragments (A-operand), pre-scaled, registers for whole kernel ----
  // A-frag lane l elem e = A[m = l&15][k = kc*32 + (l>>4)*8 + e]
  bf16x8 Wf[4][4];
  bf16x8 Wx[4];
  f32x4  c0v[4];
#pragma unroll
  for (int q = 0; q < 4; ++q) {
    const float sc = (q == 2) ? 2.0f * L2E : L2E;   // g-gate: tanh needs 2x
    const int gm = q * 128 + wid * 16 + m16;        // weight row this lane holds
#pragma unroll
    for (int kc = 0; kc < 4; ++kc) {
      const float* src = W_hh + (size_t)gm * Hdim + kc * 32 + grp * 8;
      bf16x8 w;
#pragma unroll
      for (int e = 0; e < 8; ++e) w[e] = f2bf(src[e] * sc);
      Wf[q][kc] = w;
    }
    bf16x8 w4 = {0, 0, 0, 0, 0, 0, 0, 0};  // x-chunk A: [W_ih(4)|0...] at k=0..3
    if (grp == 0) {
#pragma unroll
      for (int e = 0; e < 4; ++e) w4[e] = f2bf(W_ih[gm * Iin + e] * sc);
    }
    Wx[q] = w4;
#pragma unroll
    for (int r = 0; r < 4; ++r) {
      const int gr = q * 128 + wid * 16 + grp * 4 + r;  // this thread's gate col
      c0v[q][r] = (b_ih[gr] + b_hh[gr]) * sc;
    }
  }

  // ---- zero h buffers ----
  for (int i = tid; i < 2 * 16 * 168; i += 512) ((short*)Albuf)[i] = 0;

  const float* xrow = x + (size_t)(bbase + m16) * (Tlen * Iin);

  // ---- acc = bias + Wx @ x(0) (register-only MFMAs) ----
  // B garbage at k>=4 multiplies A==0 exactly; x finite -> 0*finite == 0.
  f32x4 acc0, acc1, acc2, acc3;
  {
    f32x4 xv = *(const f32x4*)xrow;
    uint4v u;
    u[0] = cvt_pk_bf16(xv[0], xv[1]);
    u[1] = cvt_pk_bf16(xv[2], xv[3]);
    u[2] = 0; u[3] = 0;
    union { uint4v uu; bf16x8 v; } cst; cst.uu = u;
    acc0 = MFMA(Wx[0], cst.v, c0v[0], 0, 0, 0);
    acc1 = MFMA(Wx[1], cst.v, c0v[1], 0, 0, 0);
    acc2 = MFMA(Wx[2], cst.v, c0v[2], 0, 0, 0);
    acc3 = MFMA(Wx[3], cst.v, c0v[3], 0, 0, 0);
  }

  f32x2 c4a = sp2(0.f), c4b = sp2(0.f);
  f32x2 ha = sp2(0.f), hb = sp2(0.f);
  __syncthreads();

  for (int t = 0; t < Tlen; ++t) {
    const int cur = t & 1, nxt = cur ^ 1;

    // B fragments of h(t)
    bf16x8 b0 = *(const bf16x8*)&Albuf[cur][m16][ 0 + grp * 8];
    bf16x8 b1 = *(const bf16x8*)&Albuf[cur][m16][32 + grp * 8];
    bf16x8 b2 = *(const bf16x8*)&Albuf[cur][m16][64 + grp * 8];
    bf16x8 b3 = *(const bf16x8*)&Albuf[cur][m16][96 + grp * 8];

    // x(t+1) prefetch (clamped dup-load on final step)
    const int tn = (t + 1 < Tlen) ? (t + 1) : (Tlen - 1);
    f32x4 xv = *(const f32x4*)(xrow + (size_t)tn * Iin);

    // ---- K-MAJOR MFMA issue: k0 of all 4 chains, k1, k2, k3 ----
    acc0 = MFMA(Wf[0][0], b0, acc0, 0, 0, 0);
    acc1 = MFMA(Wf[1][0], b0, acc1, 0, 0, 0);
    acc2 = MFMA(Wf[2][0], b0, acc2, 0, 0, 0);
    acc3 = MFMA(Wf[3][0], b0, acc3, 0, 0, 0);

    acc0 = MFMA(Wf[0][1], b1, acc0, 0, 0, 0);
    acc1 = MFMA(Wf[1][1], b1, acc1, 0, 0, 0);
    acc2 = MFMA(Wf[2][1], b1, acc2, 0, 0, 0);
    acc3 = MFMA(Wf[3][1], b1, acc3, 0, 0, 0);

    acc0 = MFMA(Wf[0][2], b2, acc0, 0, 0, 0);
    acc1 = MFMA(Wf[1][2], b2, acc1, 0, 0, 0);
    acc2 = MFMA(Wf[2][2], b2, acc2, 0, 0, 0);
    acc3 = MFMA(Wf[3][2], b2, acc3, 0, 0, 0);

    acc0 = MFMA(Wf[0][3], b3, acc0, 0, 0, 0);
    acc1 = MFMA(Wf[1][3], b3, acc1, 0, 0, 0);
    acc2 = MFMA(Wf[2][3], b3, acc2, 0, 0, 0);
    acc3 = MFMA(Wf[3][3], b3, acc3, 0, 0, 0);

    // ---- activations (packed-f32 Newton; no v_rcp) ----
    f32x2 si_a = sigm2(mk2(acc0[0], acc0[1]));
    f32x2 si_b = sigm2(mk2(acc0[2], acc0[3]));
    f32x2 sf_a = sigm2(mk2(acc1[0], acc1[1]));
    f32x2 sf_b = sigm2(mk2(acc1[2], acc1[3]));
    f32x2 gt_a = tanh2s(mk2(acc2[0], acc2[1]));
    f32x2 gt_b = tanh2s(mk2(acc2[2], acc2[3]));
    f32x2 so_a = sigm2(mk2(acc3[0], acc3[1]));
    f32x2 so_b = sigm2(mk2(acc3[2], acc3[3]));

    // cell + hidden update (packed fp32, in registers)
    c4a = pkfma(sf_a, c4a, si_a * gt_a);
    c4b = pkfma(sf_b, c4b, si_b * gt_b);
    f32x2 ta = tanh2s(c4a * sp2(2.8853901f));
    f32x2 tb = tanh2s(c4b * sp2(2.8853901f));
    ha = so_a * ta;
    hb = so_b * tb;

    // pack h(t+1): 4 consecutive hidden cols -> one ds_write_b64
    uint2v hp;
    hp[0] = cvt_pk_bf16(ha.x, ha.y);
    hp[1] = cvt_pk_bf16(hb.x, hb.y);
    *(uint2v*)&Albuf[nxt][m16][wid * 16 + grp * 4] = hp;

    // re-init acc = bias + Wx @ x(t+1) (register-only; drains during barrier)
    {
      uint4v u;
      u[0] = cvt_pk_bf16(xv[0], xv[1]);
      u[1] = cvt_pk_bf16(xv[2], xv[3]);
      u[2] = 0; u[3] = 0;
      union { uint4v uu; bf16x8 v; } cst; cst.uu = u;
      acc0 = MFMA(Wx[0], cst.v, c0v[0], 0, 0, 0);
      acc1 = MFMA(Wx[1], cst.v, c0v[1], 0, 0, 0);
      acc2 = MFMA(Wx[2], cst.v, c0v[2], 0, 0, 0);
      acc3 = MFMA(Wx[3], cst.v, c0v[3], 0, 0, 0);
    }

    __syncthreads();
  }

  // ---- final FC: out = h_T @ W_fc^T + b_fc ----
  {
    f32x4 hv;
    hv[0] = ha.x; hv[1] = ha.y; hv[2] = hb.x; hv[3] = hb.y;
    *(f32x4*)&hfin[m16][wid * 16 + grp * 4] = hv;
  }
  __syncthreads();
  if (tid < 64) {
    const int row = tid >> 2, o = tid & 3;
    float s = b_fc[o];
#pragma unroll 8
    for (int k = 0; k < Hdim; ++k) s += hfin[row][k] * W_fc[o * Hdim + k];
    out[(size_t)(bbase + row) * Odim + o] = s;
  }
}

extern "C" void kernel_launch(void* const* d_in, const int* in_sizes, int n_in,
                              void* d_out, int out_size, void* d_ws, size_t ws_size,
                              hipStream_t stream) {
  const float* x    = (const float*)d_in[0];
  const float* W_ih = (const float*)d_in[1];
  const float* W_hh = (const float*)d_in[2];
  const float* b_ih = (const float*)d_in[3];
  const float* b_hh = (const float*)d_in[4];
  const float* W_fc = (const float*)d_in[5];
  const float* b_fc = (const float*)d_in[6];
  float* out = (float*)d_out;
  lstm_kernel<<<64, 512, 0, stream>>>(x, W_ih, W_hh, b_ih, b_hh, W_fc, b_fc, out);
}

// Round 11
// 378.469 us; speedup vs baseline: 1.2124x; 1.2124x over previous
//
#include <hip/hip_runtime.h>
#include <hip/hip_bf16.h>

// LSTM: B=1024, T=512, I=4, H=128, O=4. Gate order i,f,g,o (PyTorch).
// out = h_T @ W_fc^T + b_fc
//
// 64 blocks x 16 batch rows, full T-loop on-chip; per step gates = W@[h|x]^T
// via mfma_f32_16x16x32_bf16 (K-major issue), x-projection as register MFMAs
// folded into next step's acc init. Thread owns 4 consecutive hidden cols of
// one batch row for all gates -> in-register c/h update.
//
// ROUND 11: r10 bisect -> r8/r9 skeleton was the NaN carrier (abandoned);
// pk-Newton activations SLOWER than trans ops (+74us) -> reverted.
// This = r7 (385us passing) + batched reciprocal: one v_rcp serves two
// sigmoids via r = rcp((1+a)(1+b)); sa = r*(1+b), sb = r*(1+a).
// rcp count 20 -> 10 per thread-step; exp2 unchanged at 20.

#define Tlen 512
#define Iin  4
#define Hdim 128
#define Odim 4

typedef __attribute__((ext_vector_type(8))) short bf16x8;
typedef __attribute__((ext_vector_type(4))) float f32x4;
typedef __attribute__((ext_vector_type(2))) unsigned uint2v;
typedef __attribute__((ext_vector_type(4))) unsigned uint4v;

static __device__ __forceinline__ short f2bf(float f) {
  union { float f; unsigned u; } v; v.f = f;
  unsigned u = v.u;
  return (short)((u + 0x7FFFu + ((u >> 16) & 1u)) >> 16);  // RNE
}
static __device__ __forceinline__ unsigned cvt_pk_bf16(float lo, float hi) {
  unsigned r;
  asm("v_cvt_pk_bf16_f32 %0, %1, %2" : "=v"(r) : "v"(lo), "v"(hi));
  return r;
}
static __device__ __forceinline__ float ex2(float x) { return __builtin_amdgcn_exp2f(x); }
static __device__ __forceinline__ float rcp_(float x) { return __builtin_amdgcn_rcpf(x); }

#define MFMA __builtin_amdgcn_mfma_f32_16x16x32_bf16

__global__ __launch_bounds__(512) void lstm_kernel(
    const float* __restrict__ x, const float* __restrict__ W_ih,
    const float* __restrict__ W_hh, const float* __restrict__ b_ih,
    const float* __restrict__ b_hh, const float* __restrict__ W_fc,
    const float* __restrict__ b_fc, float* __restrict__ out) {
  // h double-buffer: [buf][batch row][k]; row stride 168 shorts = 336 B
  // (b128-aligned; measured-benign banking). Cols 0..127 = h, rest unused/0.
  __shared__ alignas(16) short Albuf[2][16][168];
  __shared__ float hfin[16][Hdim];

  const int tid  = threadIdx.x;
  const int wid  = tid >> 6;    // wave 0..7 -> hidden cols wid*16..+15
  const int lane = tid & 63;
  const int m16  = lane & 15;   // batch row / weight row within tile
  const int grp  = lane >> 4;   // k-group 0..3
  const int bbase = blockIdx.x * 16;
  const float L2E = 1.4426950408889634f;

  // ---- weight fragments (A-operand), pre-scaled, registers for whole kernel ----
  // A-frag lane l elem e = A[m = l&15][k = kc*32 + (l>>4)*8 + e]
  bf16x8 Wf[4][4];
  bf16x8 Wx[4];
  f32x4  c0v[4];
#pragma unroll
  for (int q = 0; q < 4; ++q) {
    const float sc = (q == 2) ? 2.0f * L2E : L2E;   // g-gate: tanh needs 2x
    const int gm = q * 128 + wid * 16 + m16;        // weight row this lane holds
#pragma unroll
    for (int kc = 0; kc < 4; ++kc) {
      const float* src = W_hh + (size_t)gm * Hdim + kc * 32 + grp * 8;
      bf16x8 w;
#pragma unroll
      for (int e = 0; e < 8; ++e) w[e] = f2bf(src[e] * sc);
      Wf[q][kc] = w;
    }
    bf16x8 w4 = {0, 0, 0, 0, 0, 0, 0, 0};  // x-chunk A: [W_ih(4)|0...] at k=0..3
    if (grp == 0) {
#pragma unroll
      for (int e = 0; e < 4; ++e) w4[e] = f2bf(W_ih[gm * Iin + e] * sc);
    }
    Wx[q] = w4;
#pragma unroll
    for (int r = 0; r < 4; ++r) {
      const int gr = q * 128 + wid * 16 + grp * 4 + r;  // this thread's gate col
      c0v[q][r] = (b_ih[gr] + b_hh[gr]) * sc;
    }
  }

  // ---- zero h buffers ----
  for (int i = tid; i < 2 * 16 * 168; i += 512) ((short*)Albuf)[i] = 0;

  const float* xrow = x + (size_t)(bbase + m16) * (Tlen * Iin);

  // ---- acc = bias + Wx @ x(0) (register-only MFMAs) ----
  // B garbage at k>=4 multiplies A==0 exactly; x finite -> 0*finite == 0.
  f32x4 acc0, acc1, acc2, acc3;
  {
    f32x4 xv = *(const f32x4*)xrow;
    uint4v u;
    u[0] = cvt_pk_bf16(xv[0], xv[1]);
    u[1] = cvt_pk_bf16(xv[2], xv[3]);
    u[2] = 0; u[3] = 0;
    union { uint4v uu; bf16x8 v; } cst; cst.uu = u;
    acc0 = MFMA(Wx[0], cst.v, c0v[0], 0, 0, 0);
    acc1 = MFMA(Wx[1], cst.v, c0v[1], 0, 0, 0);
    acc2 = MFMA(Wx[2], cst.v, c0v[2], 0, 0, 0);
    acc3 = MFMA(Wx[3], cst.v, c0v[3], 0, 0, 0);
  }

  float c4[4] = {0.f, 0.f, 0.f, 0.f};
  float hl[4] = {0.f, 0.f, 0.f, 0.f};
  __syncthreads();

  for (int t = 0; t < Tlen; ++t) {
    const int cur = t & 1, nxt = cur ^ 1;

    // B fragments of h(t)
    bf16x8 b0 = *(const bf16x8*)&Albuf[cur][m16][ 0 + grp * 8];
    bf16x8 b1 = *(const bf16x8*)&Albuf[cur][m16][32 + grp * 8];
    bf16x8 b2 = *(const bf16x8*)&Albuf[cur][m16][64 + grp * 8];
    bf16x8 b3 = *(const bf16x8*)&Albuf[cur][m16][96 + grp * 8];

    // x(t+1) prefetch (clamped dup-load on final step)
    const int tn = (t + 1 < Tlen) ? (t + 1) : (Tlen - 1);
    f32x4 xv = *(const f32x4*)(xrow + (size_t)tn * Iin);

    // ---- K-MAJOR MFMA issue: k0 of all 4 chains, k1, k2, k3 ----
    acc0 = MFMA(Wf[0][0], b0, acc0, 0, 0, 0);
    acc1 = MFMA(Wf[1][0], b0, acc1, 0, 0, 0);
    acc2 = MFMA(Wf[2][0], b0, acc2, 0, 0, 0);
    acc3 = MFMA(Wf[3][0], b0, acc3, 0, 0, 0);

    acc0 = MFMA(Wf[0][1], b1, acc0, 0, 0, 0);
    acc1 = MFMA(Wf[1][1], b1, acc1, 0, 0, 0);
    acc2 = MFMA(Wf[2][1], b1, acc2, 0, 0, 0);
    acc3 = MFMA(Wf[3][1], b1, acc3, 0, 0, 0);

    acc0 = MFMA(Wf[0][2], b2, acc0, 0, 0, 0);
    acc1 = MFMA(Wf[1][2], b2, acc1, 0, 0, 0);
    acc2 = MFMA(Wf[2][2], b2, acc2, 0, 0, 0);
    acc3 = MFMA(Wf[3][2], b2, acc3, 0, 0, 0);

    acc0 = MFMA(Wf[0][3], b3, acc0, 0, 0, 0);
    acc1 = MFMA(Wf[1][3], b3, acc1, 0, 0, 0);
    acc2 = MFMA(Wf[2][3], b3, acc2, 0, 0, 0);
    acc3 = MFMA(Wf[3][3], b3, acc3, 0, 0, 0);

    // ---- activations: batched reciprocal (1 rcp per 2 sigmoids) ----
    // sigma with u=log2e*x in acc: s = 1/(1+2^-u). Pair (a,b):
    // pa=1+2^-ua, pb=1+2^-ub, r=rcp(pa*pb) -> sa=r*pb, sb=r*pa.
    f32x4 si, sf, gt, so;
    {
      float p0 = 1.0f + ex2(-acc0[0]), p1 = 1.0f + ex2(-acc0[1]);
      float p2 = 1.0f + ex2(-acc0[2]), p3 = 1.0f + ex2(-acc0[3]);
      float r01 = rcp_(p0 * p1), r23 = rcp_(p2 * p3);
      si[0] = r01 * p1; si[1] = r01 * p0; si[2] = r23 * p3; si[3] = r23 * p2;
    }
    {
      float p0 = 1.0f + ex2(-acc1[0]), p1 = 1.0f + ex2(-acc1[1]);
      float p2 = 1.0f + ex2(-acc1[2]), p3 = 1.0f + ex2(-acc1[3]);
      float r01 = rcp_(p0 * p1), r23 = rcp_(p2 * p3);
      sf[0] = r01 * p1; sf[1] = r01 * p0; sf[2] = r23 * p3; sf[3] = r23 * p2;
    }
    {
      // tanh with u=2*log2e*z in acc2: tanh = 2/(1+2^-u) - 1
      float p0 = 1.0f + ex2(-acc2[0]), p1 = 1.0f + ex2(-acc2[1]);
      float p2 = 1.0f + ex2(-acc2[2]), p3 = 1.0f + ex2(-acc2[3]);
      float r01 = rcp_(p0 * p1), r23 = rcp_(p2 * p3);
      float r01_2 = r01 + r01, r23_2 = r23 + r23;
      gt[0] = __builtin_fmaf(r01_2, p1, -1.0f);
      gt[1] = __builtin_fmaf(r01_2, p0, -1.0f);
      gt[2] = __builtin_fmaf(r23_2, p3, -1.0f);
      gt[3] = __builtin_fmaf(r23_2, p2, -1.0f);
    }
    {
      float p0 = 1.0f + ex2(-acc3[0]), p1 = 1.0f + ex2(-acc3[1]);
      float p2 = 1.0f + ex2(-acc3[2]), p3 = 1.0f + ex2(-acc3[3]);
      float r01 = rcp_(p0 * p1), r23 = rcp_(p2 * p3);
      so[0] = r01 * p1; so[1] = r01 * p0; so[2] = r23 * p3; so[3] = r23 * p2;
    }

    // cell update, then paired cell-tanh
#pragma unroll
    for (int r = 0; r < 4; ++r)
      c4[r] = __builtin_fmaf(sf[r], c4[r], si[r] * gt[r]);
    {
      float p0 = 1.0f + ex2(-2.8853900817779268f * c4[0]);
      float p1 = 1.0f + ex2(-2.8853900817779268f * c4[1]);
      float p2 = 1.0f + ex2(-2.8853900817779268f * c4[2]);
      float p3 = 1.0f + ex2(-2.8853900817779268f * c4[3]);
      float r01 = rcp_(p0 * p1), r23 = rcp_(p2 * p3);
      float r01_2 = r01 + r01, r23_2 = r23 + r23;
      hl[0] = so[0] * __builtin_fmaf(r01_2, p1, -1.0f);
      hl[1] = so[1] * __builtin_fmaf(r01_2, p0, -1.0f);
      hl[2] = so[2] * __builtin_fmaf(r23_2, p3, -1.0f);
      hl[3] = so[3] * __builtin_fmaf(r23_2, p2, -1.0f);
    }

    // pack h(t+1): 4 consecutive hidden cols -> one ds_write_b64
    uint2v hp;
    hp[0] = cvt_pk_bf16(hl[0], hl[1]);
    hp[1] = cvt_pk_bf16(hl[2], hl[3]);
    *(uint2v*)&Albuf[nxt][m16][wid * 16 + grp * 4] = hp;

    // re-init acc = bias + Wx @ x(t+1) (register-only; drains during barrier)
    {
      uint4v u;
      u[0] = cvt_pk_bf16(xv[0], xv[1]);
      u[1] = cvt_pk_bf16(xv[2], xv[3]);
      u[2] = 0; u[3] = 0;
      union { uint4v uu; bf16x8 v; } cst; cst.uu = u;
      acc0 = MFMA(Wx[0], cst.v, c0v[0], 0, 0, 0);
      acc1 = MFMA(Wx[1], cst.v, c0v[1], 0, 0, 0);
      acc2 = MFMA(Wx[2], cst.v, c0v[2], 0, 0, 0);
      acc3 = MFMA(Wx[3], cst.v, c0v[3], 0, 0, 0);
    }

    __syncthreads();
  }

  // ---- final FC: out = h_T @ W_fc^T + b_fc ----
  {
    f32x4 hv;
    hv[0] = hl[0]; hv[1] = hl[1]; hv[2] = hl[2]; hv[3] = hl[3];
    *(f32x4*)&hfin[m16][wid * 16 + grp * 4] = hv;
  }
  __syncthreads();
  if (tid < 64) {
    const int row = tid >> 2, o = tid & 3;
    float s = b_fc[o];
#pragma unroll 8
    for (int k = 0; k < Hdim; ++k) s += hfin[row][k] * W_fc[o * Hdim + k];
    out[(size_t)(bbase + row) * Odim + o] = s;
  }
}

extern "C" void kernel_launch(void* const* d_in, const int* in_sizes, int n_in,
                              void* d_out, int out_size, void* d_ws, size_t ws_size,
                              hipStream_t stream) {
  const float* x    = (const float*)d_in[0];
  const float* W_ih = (const float*)d_in[1];
  const float* W_hh = (const float*)d_in[2];
  const float* b_ih = (const float*)d_in[3];
  const float* b_hh = (const float*)d_in[4];
  const float* W_fc = (const float*)d_in[5];
  const float* b_fc = (const float*)d_in[6];
  float* out = (float*)d_out;
  lstm_kernel<<<64, 512, 0, stream>>>(x, W_ih, W_hh, b_ih, b_hh, W_fc, b_fc, out);
}

// Round 12
// 371.545 us; speedup vs baseline: 1.2350x; 1.0186x over previous
//
#include <hip/hip_runtime.h>
#include <hip/hip_bf16.h>

// LSTM: B=1024, T=512, I=4, H=128, O=4. Gate order i,f,g,o (PyTorch).
// out = h_T @ W_fc^T + b_fc
//
// 64 blocks x 16 batch rows, full T-loop on-chip; per step gates = W@[h|x]^T
// via mfma_f32_16x16x32_bf16, x-projection folded into acc init (register
// MFMAs at end of previous step). Thread owns 4 consecutive hidden cols of
// one batch row for all gates -> in-register c/h update. Batched reciprocal
// (1 v_rcp per 2 sigmoids) from r11.
//
// ROUND 12: r7-r11 PMC -> pipes serial (M 620 + V 1070 ~= step 1770) due to
// IN-ORDER ISSUE BACKPRESSURE: with all MFMAs textually first, a wave issues
// 16 MFMAs (620 cyc at shared pipe rate) before its first sigma can issue.
// Fix: chain-major MFMA chains with activations WOVEN BETWEEN chains, pinned
// with __builtin_amdgcn_sched_barrier(0) so the compiler cannot sink VALU
// below MFMAs (r5's failure) -- wave A's sigma overlaps wave B's chains.
// Arithmetic is bit-identical to r11 (pure reorder + pins).

#define Tlen 512
#define Iin  4
#define Hdim 128
#define Odim 4

#define SB0() __builtin_amdgcn_sched_barrier(0)

typedef __attribute__((ext_vector_type(8))) short bf16x8;
typedef __attribute__((ext_vector_type(4))) float f32x4;
typedef __attribute__((ext_vector_type(2))) unsigned uint2v;
typedef __attribute__((ext_vector_type(4))) unsigned uint4v;

static __device__ __forceinline__ short f2bf(float f) {
  union { float f; unsigned u; } v; v.f = f;
  unsigned u = v.u;
  return (short)((u + 0x7FFFu + ((u >> 16) & 1u)) >> 16);  // RNE
}
static __device__ __forceinline__ unsigned cvt_pk_bf16(float lo, float hi) {
  unsigned r;
  asm("v_cvt_pk_bf16_f32 %0, %1, %2" : "=v"(r) : "v"(lo), "v"(hi));
  return r;
}
static __device__ __forceinline__ float ex2(float x) { return __builtin_amdgcn_exp2f(x); }
static __device__ __forceinline__ float rcp_(float x) { return __builtin_amdgcn_rcpf(x); }

#define MFMA __builtin_amdgcn_mfma_f32_16x16x32_bf16

__global__ __launch_bounds__(512) void lstm_kernel(
    const float* __restrict__ x, const float* __restrict__ W_ih,
    const float* __restrict__ W_hh, const float* __restrict__ b_ih,
    const float* __restrict__ b_hh, const float* __restrict__ W_fc,
    const float* __restrict__ b_fc, float* __restrict__ out) {
  // h double-buffer: [buf][batch row][k]; row stride 168 shorts = 336 B.
  __shared__ alignas(16) short Albuf[2][16][168];
  __shared__ float hfin[16][Hdim];

  const int tid  = threadIdx.x;
  const int wid  = tid >> 6;    // wave 0..7 -> hidden cols wid*16..+15
  const int lane = tid & 63;
  const int m16  = lane & 15;   // batch row / weight row within tile
  const int grp  = lane >> 4;   // k-group 0..3
  const int bbase = blockIdx.x * 16;
  const float L2E = 1.4426950408889634f;

  // ---- weight fragments (A-operand), pre-scaled, registers for whole kernel ----
  bf16x8 Wf[4][4];
  bf16x8 Wx[4];
  f32x4  c0v[4];
#pragma unroll
  for (int q = 0; q < 4; ++q) {
    const float sc = (q == 2) ? 2.0f * L2E : L2E;   // g-gate: tanh needs 2x
    const int gm = q * 128 + wid * 16 + m16;        // weight row this lane holds
#pragma unroll
    for (int kc = 0; kc < 4; ++kc) {
      const float* src = W_hh + (size_t)gm * Hdim + kc * 32 + grp * 8;
      bf16x8 w;
#pragma unroll
      for (int e = 0; e < 8; ++e) w[e] = f2bf(src[e] * sc);
      Wf[q][kc] = w;
    }
    bf16x8 w4 = {0, 0, 0, 0, 0, 0, 0, 0};  // x-chunk A: [W_ih(4)|0...] at k=0..3
    if (grp == 0) {
#pragma unroll
      for (int e = 0; e < 4; ++e) w4[e] = f2bf(W_ih[gm * Iin + e] * sc);
    }
    Wx[q] = w4;
#pragma unroll
    for (int r = 0; r < 4; ++r) {
      const int gr = q * 128 + wid * 16 + grp * 4 + r;  // this thread's gate col
      c0v[q][r] = (b_ih[gr] + b_hh[gr]) * sc;
    }
  }

  // ---- zero h buffers ----
  for (int i = tid; i < 2 * 16 * 168; i += 512) ((short*)Albuf)[i] = 0;

  const float* xrow = x + (size_t)(bbase + m16) * (Tlen * Iin);

  // ---- acc = bias + Wx @ x(0) (register-only MFMAs) ----
  f32x4 acc0, acc1, acc2, acc3;
  {
    f32x4 xv = *(const f32x4*)xrow;
    uint4v u;
    u[0] = cvt_pk_bf16(xv[0], xv[1]);
    u[1] = cvt_pk_bf16(xv[2], xv[3]);
    u[2] = 0; u[3] = 0;
    union { uint4v uu; bf16x8 v; } cst; cst.uu = u;
    acc0 = MFMA(Wx[0], cst.v, c0v[0], 0, 0, 0);
    acc1 = MFMA(Wx[1], cst.v, c0v[1], 0, 0, 0);
    acc2 = MFMA(Wx[2], cst.v, c0v[2], 0, 0, 0);
    acc3 = MFMA(Wx[3], cst.v, c0v[3], 0, 0, 0);
  }

  float c4[4] = {0.f, 0.f, 0.f, 0.f};
  float hl[4] = {0.f, 0.f, 0.f, 0.f};
  __syncthreads();

  for (int t = 0; t < Tlen; ++t) {
    const int cur = t & 1, nxt = cur ^ 1;

    // B fragments of h(t); x(t+1) prefetch
    bf16x8 b0 = *(const bf16x8*)&Albuf[cur][m16][ 0 + grp * 8];
    bf16x8 b1 = *(const bf16x8*)&Albuf[cur][m16][32 + grp * 8];
    bf16x8 b2 = *(const bf16x8*)&Albuf[cur][m16][64 + grp * 8];
    bf16x8 b3 = *(const bf16x8*)&Albuf[cur][m16][96 + grp * 8];
    const int tn = (t + 1 < Tlen) ? (t + 1) : (Tlen - 1);
    f32x4 xv = *(const f32x4*)(xrow + (size_t)tn * Iin);

    // ---- software-pipelined chains: q0,q1 | si | q2 | sf | q3 | gt | so ----
    // chain q0 (k-serial), chain q1
    acc0 = MFMA(Wf[0][0], b0, acc0, 0, 0, 0);
    acc0 = MFMA(Wf[0][1], b1, acc0, 0, 0, 0);
    acc0 = MFMA(Wf[0][2], b2, acc0, 0, 0, 0);
    acc0 = MFMA(Wf[0][3], b3, acc0, 0, 0, 0);
    acc1 = MFMA(Wf[1][0], b0, acc1, 0, 0, 0);
    acc1 = MFMA(Wf[1][1], b1, acc1, 0, 0, 0);
    acc1 = MFMA(Wf[1][2], b2, acc1, 0, 0, 0);
    acc1 = MFMA(Wf[1][3], b3, acc1, 0, 0, 0);
    SB0();
    // sigma_i from acc0 (batched rcp)
    f32x4 si;
    {
      float p0 = 1.0f + ex2(-acc0[0]), p1 = 1.0f + ex2(-acc0[1]);
      float p2 = 1.0f + ex2(-acc0[2]), p3 = 1.0f + ex2(-acc0[3]);
      float r01 = rcp_(p0 * p1), r23 = rcp_(p2 * p3);
      si[0] = r01 * p1; si[1] = r01 * p0; si[2] = r23 * p3; si[3] = r23 * p2;
    }
    SB0();
    // chain q2
    acc2 = MFMA(Wf[2][0], b0, acc2, 0, 0, 0);
    acc2 = MFMA(Wf[2][1], b1, acc2, 0, 0, 0);
    acc2 = MFMA(Wf[2][2], b2, acc2, 0, 0, 0);
    acc2 = MFMA(Wf[2][3], b3, acc2, 0, 0, 0);
    SB0();
    // sigma_f from acc1
    f32x4 sf;
    {
      float p0 = 1.0f + ex2(-acc1[0]), p1 = 1.0f + ex2(-acc1[1]);
      float p2 = 1.0f + ex2(-acc1[2]), p3 = 1.0f + ex2(-acc1[3]);
      float r01 = rcp_(p0 * p1), r23 = rcp_(p2 * p3);
      sf[0] = r01 * p1; sf[1] = r01 * p0; sf[2] = r23 * p3; sf[3] = r23 * p2;
    }
    SB0();
    // chain q3
    acc3 = MFMA(Wf[3][0], b0, acc3, 0, 0, 0);
    acc3 = MFMA(Wf[3][1], b1, acc3, 0, 0, 0);
    acc3 = MFMA(Wf[3][2], b2, acc3, 0, 0, 0);
    acc3 = MFMA(Wf[3][3], b3, acc3, 0, 0, 0);
    SB0();
    // tanh_g from acc2 (u = 2*log2e*z pre-scaled)
    f32x4 gt;
    {
      float p0 = 1.0f + ex2(-acc2[0]), p1 = 1.0f + ex2(-acc2[1]);
      float p2 = 1.0f + ex2(-acc2[2]), p3 = 1.0f + ex2(-acc2[3]);
      float r01 = rcp_(p0 * p1), r23 = rcp_(p2 * p3);
      float r01_2 = r01 + r01, r23_2 = r23 + r23;
      gt[0] = __builtin_fmaf(r01_2, p1, -1.0f);
      gt[1] = __builtin_fmaf(r01_2, p0, -1.0f);
      gt[2] = __builtin_fmaf(r23_2, p3, -1.0f);
      gt[3] = __builtin_fmaf(r23_2, p2, -1.0f);
    }
    SB0();
    // sigma_o from acc3
    f32x4 so;
    {
      float p0 = 1.0f + ex2(-acc3[0]), p1 = 1.0f + ex2(-acc3[1]);
      float p2 = 1.0f + ex2(-acc3[2]), p3 = 1.0f + ex2(-acc3[3]);
      float r01 = rcp_(p0 * p1), r23 = rcp_(p2 * p3);
      so[0] = r01 * p1; so[1] = r01 * p0; so[2] = r23 * p3; so[3] = r23 * p2;
    }

    // cell update + paired cell-tanh
#pragma unroll
    for (int r = 0; r < 4; ++r)
      c4[r] = __builtin_fmaf(sf[r], c4[r], si[r] * gt[r]);
    {
      float p0 = 1.0f + ex2(-2.8853900817779268f * c4[0]);
      float p1 = 1.0f + ex2(-2.8853900817779268f * c4[1]);
      float p2 = 1.0f + ex2(-2.8853900817779268f * c4[2]);
      float p3 = 1.0f + ex2(-2.8853900817779268f * c4[3]);
      float r01 = rcp_(p0 * p1), r23 = rcp_(p2 * p3);
      float r01_2 = r01 + r01, r23_2 = r23 + r23;
      hl[0] = so[0] * __builtin_fmaf(r01_2, p1, -1.0f);
      hl[1] = so[1] * __builtin_fmaf(r01_2, p0, -1.0f);
      hl[2] = so[2] * __builtin_fmaf(r23_2, p3, -1.0f);
      hl[3] = so[3] * __builtin_fmaf(r23_2, p2, -1.0f);
    }

    // pack h(t+1): one ds_write_b64
    uint2v hp;
    hp[0] = cvt_pk_bf16(hl[0], hl[1]);
    hp[1] = cvt_pk_bf16(hl[2], hl[3]);
    *(uint2v*)&Albuf[nxt][m16][wid * 16 + grp * 4] = hp;

    // re-init acc = bias + Wx @ x(t+1) (register-only; drains during barrier)
    {
      uint4v u;
      u[0] = cvt_pk_bf16(xv[0], xv[1]);
      u[1] = cvt_pk_bf16(xv[2], xv[3]);
      u[2] = 0; u[3] = 0;
      union { uint4v uu; bf16x8 v; } cst; cst.uu = u;
      acc0 = MFMA(Wx[0], cst.v, c0v[0], 0, 0, 0);
      acc1 = MFMA(Wx[1], cst.v, c0v[1], 0, 0, 0);
      acc2 = MFMA(Wx[2], cst.v, c0v[2], 0, 0, 0);
      acc3 = MFMA(Wx[3], cst.v, c0v[3], 0, 0, 0);
    }

    __syncthreads();
  }

  // ---- final FC: out = h_T @ W_fc^T + b_fc ----
  {
    f32x4 hv;
    hv[0] = hl[0]; hv[1] = hl[1]; hv[2] = hl[2]; hv[3] = hl[3];
    *(f32x4*)&hfin[m16][wid * 16 + grp * 4] = hv;
  }
  __syncthreads();
  if (tid < 64) {
    const int row = tid >> 2, o = tid & 3;
    float s = b_fc[o];
#pragma unroll 8
    for (int k = 0; k < Hdim; ++k) s += hfin[row][k] * W_fc[o * Hdim + k];
    out[(size_t)(bbase + row) * Odim + o] = s;
  }
}

extern "C" void kernel_launch(void* const* d_in, const int* in_sizes, int n_in,
                              void* d_out, int out_size, void* d_ws, size_t ws_size,
                              hipStream_t stream) {
  const float* x    = (const float*)d_in[0];
  const float* W_ih = (const float*)d_in[1];
  const float* W_hh = (const float*)d_in[2];
  const float* b_ih = (const float*)d_in[3];
  const float* b_hh = (const float*)d_in[4];
  const float* W_fc = (const float*)d_in[5];
  const float* b_fc = (const float*)d_in[6];
  float* out = (float*)d_out;
  lstm_kernel<<<64, 512, 0, stream>>>(x, W_ih, W_hh, b_ih, b_hh, W_fc, b_fc, out);
}